// Round 1
// baseline (646.220 us; speedup 1.0000x reference)
//
#include <hip/hip_runtime.h>
#include <hip/hip_bf16.h>

// Problem constants (from reference): memory [E, M, D] fp32
constexpr int E = 1024;
constexpr int M = 200;
constexpr int D = 512;
constexpr long long TOT = (long long)E * M * D;   // 104,857,600 floats
constexpr int N4 = (int)(TOT / 4);                 // 26,214,400 float4s
constexpr int PER_ENV4 = M * D / 4;                // 25,600 float4 per env
constexpr int PER_ROW4 = D / 4;                    // 128 float4 per row
constexpr float NOVELTY_THRESHOLD = 0.5f;

__global__ __launch_bounds__(256) void reach_update(
    const float4* __restrict__ mem,     // [E*M*D/4]
    const float4* __restrict__ obs,     // [E*D/4]
    const float*  __restrict__ sim,     // [E]
    const int*    __restrict__ mask,    // [E]
    const int*    __restrict__ ridx,    // [E]
    float4*       __restrict__ out_mem, // [E*M*D/4]
    float*        __restrict__ out_mask // [E], written as float values
) {
    int i4 = blockIdx.x * blockDim.x + threadIdx.x;
    if (i4 >= N4) return;

    int e    = i4 / PER_ENV4;             // magic-mul division (constant)
    int rem  = i4 - e * PER_ENV4;
    int row  = rem >> 7;                  // / PER_ROW4 (128)
    int col4 = rem & (PER_ROW4 - 1);

    // Per-env metadata: tiny (4 KB) arrays, L1-resident, wave-uniform e.
    float s   = sim[e];
    int   mk  = mask[e];
    bool  add  = s > NOVELTY_THRESHOLD;
    bool  full = (mk == M);
    int   nm   = mk + ((!full) && add ? 1 : 0);
    int   am1  = nm - 1; if (am1 < 0) am1 = 0;
    int   idx  = full ? ridx[e] : am1;

    float4 v = mem[i4];
    if (add && row == idx) {
        v = obs[e * PER_ROW4 + col4];
    }
    out_mem[i4] = v;

    // First E threads also emit the updated counter (as float; exact for <=201).
    if (i4 < E) {
        int   mk2   = mask[i4];
        bool  add2  = sim[i4] > NOVELTY_THRESHOLD;
        bool  full2 = (mk2 == M);
        int   nm2   = mk2 + ((!full2) && add2 ? 1 : 0);
        out_mask[i4] = (float)nm2;
    }
}

extern "C" void kernel_launch(void* const* d_in, const int* in_sizes, int n_in,
                              void* d_out, int out_size, void* d_ws, size_t ws_size,
                              hipStream_t stream) {
    const float4* mem  = (const float4*)d_in[0];
    const float4* obs  = (const float4*)d_in[1];
    const float*  sim  = (const float*)d_in[2];
    const int*    mask = (const int*)d_in[3];
    const int*    ridx = (const int*)d_in[4];

    float* out      = (float*)d_out;
    float* out_mask = out + TOT;   // mask tail starts after the memory bank

    constexpr int BLOCK = 256;
    int grid = (N4 + BLOCK - 1) / BLOCK;   // 102,400 blocks
    reach_update<<<grid, BLOCK, 0, stream>>>(mem, obs, sim, mask, ridx,
                                             (float4*)out, out_mask);
}